// Round 4
// baseline (636.277 us; speedup 1.0000x reference)
//
#include <hip/hip_runtime.h>

#define NB 4
#define CIN 64
#define COUT 64
#define H 128
#define W 128
#define H2 256
#define W2 256

// ws layout (float units)
#define WS_P1   0         // per-tile partial sums  [4*64][128]
#define WS_P2   32768     // per-tile partial sumsq
#define WS_MU   65536
#define WS_RSTD 65792
#define WS_W    66048     // pre-transposed bf16 weights: ushort[32][64][32]

// ---------------------------------------------------------------------------
// Compile-time DISCO basis (replicates the numpy double-precision computation)
// ---------------------------------------------------------------------------
constexpr double csqrt(double x) {
    double g = x > 1.0 ? x : 1.0;
    for (int i = 0; i < 64; ++i) g = 0.5 * (g + x / g);
    return g;
}
constexpr double catan_pos(double x) {
    double f = 1.0;
    for (int i = 0; i < 6; ++i) { x = x / (1.0 + csqrt(1.0 + x * x)); f *= 2.0; }
    double x2 = x * x, s = 0.0, term = x;
    for (int n = 0; n < 10; ++n) { s += term / (2 * n + 1) * ((n & 1) ? -1.0 : 1.0); term *= x2; }
    return f * s;
}
constexpr double catan2c(double y, double x) {
    const double PI = 3.141592653589793;
    if (x == 0.0 && y == 0.0) return 0.0;
    double ax = x < 0 ? -x : x, ay = y < 0 ? -y : y;
    double a = (ax >= ay) ? catan_pos(ay / ax) : (PI / 2.0 - catan_pos(ax / ay));
    if (x < 0) a = PI - a;
    return (y < 0) ? -a : a;
}

struct PsiTab { double v[81][9]; };
constexpr PsiTab compute_psi() {
    PsiTab P{};
    const double hy = 1.0 / 256.0;
    const double rcut = 0.015;
    const double dr = 0.0075;
    const double PI = 3.141592653589793;
    const double TWO_PI = 6.283185307179586;
    const double dphi = PI / 2.0;
    for (int ky = 0; ky < 9; ++ky)
        for (int kx = 0; kx < 9; ++kx) {
            double dy = (double)(ky - 4) * hy;
            double dx = (double)(kx - 4) * hy;
            double r = csqrt(dy * dy + dx * dx);
            double phi = catan2c(dy, dx);
            if (phi < 0.0) phi += TWO_PI;
            for (int k = 0; k < 9; ++k) {
                int ir = (k == 0) ? 0 : ((k - 1) / 4 + 1);
                double ctr = ir * dr;
                double ad = r > ctr ? r - ctr : ctr - r;
                double rv = (ad <= dr && r <= rcut) ? 1.0 - ad / dr : 0.0;
                double val;
                if (k == 0) val = rv;
                else {
                    int ip = (k - 1) % 4;
                    double da = phi - ip * dphi; if (da < 0) da = -da;
                    double d2 = TWO_PI - da; if (d2 < da) da = d2;
                    double pv = (da <= dphi) ? 1.0 - da / dphi : 0.0;
                    val = rv * pv;
                }
                P.v[ky * 9 + kx][k] = val * (hy * hy);
            }
        }
    return P;
}

struct TapTab {
    int nt;
    int off[48];          // dy*23 + dx (u32 offset from thread base in halo)
    float val[48][9];
    bool nz[48][9];
};
constexpr TapTab make_taps() {
    TapTab T{};
    PsiTab P = compute_psi();
    for (int ky = 0; ky < 9; ++ky)
        for (int kx = 0; kx < 9; ++kx) {
            int t = ky * 9 + kx;
            bool any = false;
            for (int k = 0; k < 9; ++k) if (P.v[t][k] != 0.0) any = true;
            if (!any) continue;
            int dy = ky - 4, dx = kx - 4;    // support guarantees |dy|,|dx| <= 3
            T.off[T.nt] = dy * 23 + dx;
            for (int k = 0; k < 9; ++k) {
                T.val[T.nt][k] = (float)P.v[t][k];
                T.nz[T.nt][k] = (P.v[t][k] != 0.0);
            }
            T.nt++;
        }
    return T;
}
constexpr TapTab TT = make_taps();
constexpr int NT = TT.nt;
static_assert(NT > 0 && NT <= 48, "tap table overflow");

using f32x4  = __attribute__((ext_vector_type(4))) float;
using bf16x8 = __attribute__((ext_vector_type(8))) short;

__device__ __forceinline__ unsigned short f2bf_rne(float f) {
    unsigned u = __float_as_uint(f);
    unsigned r = (u + 0x7fff + ((u >> 16) & 1)) >> 16;
    return (unsigned short)r;
}
// RTZ pack of two floats to one u32 of 2 bf16 (bias cancels in InstanceNorm)
__device__ __forceinline__ unsigned pkrtz(float a, float b) {
    return (__float_as_uint(a) >> 16) | (__float_as_uint(b) & 0xffff0000u);
}

// ---------------------------------------------------------------------------
// Setup: pre-transpose weights to bf16 wsW[g][o][32]  (kk = ch*16 + k, pads 0)
// ---------------------------------------------------------------------------
__global__ void setup_w(const float* __restrict__ wgt, float* __restrict__ ws) {
    unsigned short* wsW = (unsigned short*)(ws + WS_W);
    const int g = blockIdx.x;          // channel pair 0..31
    const int t = threadIdx.x;         // 256
    const int o = t >> 2;
    const int k0 = (t & 3) * 8;
#pragma unroll
    for (int j = 0; j < 8; ++j) {
        int kk = k0 + j;
        int ch = kk >> 4, k = kk & 15;
        float v = (k < 9) ? wgt[((size_t)o * CIN + 2 * g + ch) * 9 + k] : 0.f;
        wsW[g * 2048 + o * 32 + kk] = f2bf_rne(v);
    }
}

// ---------------------------------------------------------------------------
// Fused upsample + DISCO conv. Block = 16x32 px tile (512 px), 4 waves.
// Thread owns px pair (32r+c, 32r+c+16). Halo staged as bf16 PIXEL-PAIRED
// dwords {val(x), val(x+16)} so one ds_read_b32 feeds both pixels' tap.
// zbuf bf16 [512][40] -> MFMA 16x16x32 over K = 2ch x 16 (pads zero).
// ---------------------------------------------------------------------------
__global__ __launch_bounds__(256, 2) void conv_kernel(const float* __restrict__ img,
                                                      float* __restrict__ out,
                                                      float* __restrict__ ws) {
    __shared__ unsigned short zbuf[512][40];   // [px][kk] bf16, 80B row (16-aligned)
    __shared__ unsigned halo[2][2][506];       // [buf][ch][22*23] px-paired bf16x2
    __shared__ float red1[4][64], red2[4][64];

    const int tid  = threadIdx.x;
    const int bid  = blockIdx.x;
    const int n    = bid >> 7;
    const int tile = bid & 127;
    const int ty0  = (tile >> 3) << 4;     // 16 tile-rows
    const int tx0  = (tile & 7) << 5;      // 8 tile-cols (32 wide)

    const int r = tid >> 4, c = tid & 15;
    const int hbase = (r + 3) * 23 + (c + 3);
    const int px0 = 32 * r + c;
    const int wv  = tid >> 6;
    const int l   = tid & 63;
    const int a16 = l & 15;
    const int kseg = (l >> 4) * 8;

    const unsigned short* wsW = (const unsigned short*)(ws + WS_W);

    // zero zbuf once (pads stay zero forever)
    {
        uint4* zr = (uint4*)&zbuf[0][0];
#pragma unroll
        for (int j = 0; j < 10; ++j) zr[tid + j * 256] = make_uint4(0, 0, 0, 0);
    }

    const float cs = (float)(127.0 / 255.0);

    // stage halo for channel pair g into buf b (bf16 RNE, pixel-paired dwords)
    auto stage = [&](int g, int b) {
        const float* im0 = img + ((size_t)n * CIN + 2 * g) * (H * W);
#pragma unroll
        for (int j = 0; j < 7; ++j) {
            int e = tid + j * 256;
            if (e < 1672) {
                int ch = (e >= 836) ? 1 : 0;
                int e2 = e - ch * 836;
                int hy = e2 / 38, f = e2 - hy * 38;
                int uy = ty0 - 3 + hy, ux = tx0 - 3 + f;
                bool zf = ((unsigned)uy >= 256u) || ((unsigned)ux >= 256u);
                float syf = (float)uy * cs;
                float sxf = (float)ux * cs;
                int y0 = (int)syf; y0 = min(max(y0, 0), 127);
                int x0 = (int)sxf; x0 = min(max(x0, 0), 127);
                int y1 = min(y0 + 1, 127);
                int x1 = min(x0 + 1, 127);
                float fy = syf - (float)y0;
                float fx = sxf - (float)x0;
                const float* imc = im0 + ch * (H * W);
                float a00 = imc[y0 * W + x0], a01 = imc[y0 * W + x1];
                float a10 = imc[y1 * W + x0], a11 = imc[y1 * W + x1];
                float t0 = a00 + fy * (a10 - a00);
                float t1 = a01 + fy * (a11 - a01);
                float v = t0 + fx * (t1 - t0);
                v = zf ? 0.f : v;
                unsigned short bv = f2bf_rne(v);
                unsigned short* hp = (unsigned short*)&halo[b][ch][0];
                int base = hy * 23;
                if (f <= 21) hp[(base + f) * 2] = bv;           // lo half of dword f
                if (f >= 16) hp[(base + f - 16) * 2 + 1] = bv;  // hi half of dword f-16
            }
        }
    };

    // z for both pixels of this thread, channel-slot s, halo buf b
    auto zphase = [&](int b, int s) {
        const unsigned* hb = &halo[b][s][0] + hbase;
        float zl[9] = {0.f,0.f,0.f,0.f,0.f,0.f,0.f,0.f,0.f};
        float zh[9] = {0.f,0.f,0.f,0.f,0.f,0.f,0.f,0.f,0.f};
#pragma unroll
        for (int t = 0; t < NT; ++t) {
            unsigned d = hb[TT.off[t]];
            float lo = __uint_as_float(d << 16);
            float hi = __uint_as_float(d & 0xffff0000u);
#pragma unroll
            for (int k = 0; k < 9; ++k)
                if (TT.nz[t][k]) {
                    zl[k] = fmaf(TT.val[t][k], lo, zl[k]);
                    zh[k] = fmaf(TT.val[t][k], hi, zh[k]);
                }
        }
        uint4 pl = make_uint4(pkrtz(zl[0], zl[1]), pkrtz(zl[2], zl[3]),
                              pkrtz(zl[4], zl[5]), pkrtz(zl[6], zl[7]));
        *(uint4*)&zbuf[px0][s * 16] = pl;
        *(unsigned*)&zbuf[px0][s * 16 + 8] = __float_as_uint(zl[8]) >> 16;
        uint4 ph = make_uint4(pkrtz(zh[0], zh[1]), pkrtz(zh[2], zh[3]),
                              pkrtz(zh[4], zh[5]), pkrtz(zh[6], zh[7]));
        *(uint4*)&zbuf[px0 + 16][s * 16] = ph;
        *(unsigned*)&zbuf[px0 + 16][s * 16 + 8] = __float_as_uint(zh[8]) >> 16;
    };

    f32x4 acc[4][8];
#pragma unroll
    for (int m = 0; m < 4; ++m)
#pragma unroll
        for (int t = 0; t < 8; ++t) acc[m][t] = (f32x4){0.f, 0.f, 0.f, 0.f};

    stage(0, 0);
    int cur = 0;

#pragma unroll 1
    for (int g = 0; g < 32; ++g) {
        __syncthreads();   // halo[cur] staged; zbuf reads of prev iter done
        // A-fragments direct from global (L2-hot), issued early
        bf16x8 af[4];
        {
            const unsigned short* wp = wsW + g * 2048 + a16 * 32 + kseg;
#pragma unroll
            for (int m = 0; m < 4; ++m)
                af[m] = *(const bf16x8*)(wp + m * 512);
        }
        if (g < 31) stage(g + 1, cur ^ 1);   // overlaps zphase
        zphase(cur, 0);
        zphase(cur, 1);
        __syncthreads();   // zbuf written

        bf16x8 bfr[8];
#pragma unroll
        for (int t = 0; t < 8; ++t)
            bfr[t] = *(const bf16x8*)&zbuf[wv * 128 + t * 16 + a16][kseg];
#pragma unroll
        for (int m = 0; m < 4; ++m)
#pragma unroll
            for (int t = 0; t < 8; ++t)
                acc[m][t] = __builtin_amdgcn_mfma_f32_16x16x32_bf16(af[m], bfr[t], acc[m][t], 0, 0, 0);
        cur ^= 1;
    }

    // ---- epilogue: instance-norm partials + store y ----
#pragma unroll
    for (int m = 0; m < 4; ++m) {
#pragma unroll
        for (int r4 = 0; r4 < 4; ++r4) {
            float s = 0.f, q = 0.f;
#pragma unroll
            for (int t = 0; t < 8; ++t) {
                float v = acc[m][t][r4];
                s += v; q = fmaf(v, v, q);
            }
#pragma unroll
            for (int msk = 1; msk < 16; msk <<= 1) {
                s += __shfl_xor(s, msk);
                q += __shfl_xor(q, msk);
            }
            if (a16 == 0) {
                int o = m * 16 + (l >> 4) * 4 + r4;
                red1[wv][o] = s;
                red2[wv][o] = q;
            }
        }
    }

    const size_t nbase = (size_t)n * COUT * (H2 * W2);
#pragma unroll
    for (int m = 0; m < 4; ++m)
#pragma unroll
        for (int t = 0; t < 8; ++t) {
            int Y = ty0 + wv * 4 + (t >> 1);
            int X = tx0 + (t & 1) * 16 + a16;
#pragma unroll
            for (int r4 = 0; r4 < 4; ++r4) {
                int o = m * 16 + (l >> 4) * 4 + r4;
                out[nbase + (size_t)o * (H2 * W2) + Y * W2 + X] = acc[m][t][r4];
            }
        }
    __syncthreads();
    if (tid < 64) {
        float S1 = red1[0][tid] + red1[1][tid] + red1[2][tid] + red1[3][tid];
        float S2 = red2[0][tid] + red2[1][tid] + red2[2][tid] + red2[3][tid];
        ws[WS_P1 + (n * COUT + tid) * 128 + tile] = S1;
        ws[WS_P2 + (n * COUT + tid) * 128 + tile] = S2;
    }
}

// ---------------------------------------------------------------------------
// Stats: reduce 128 tile-partials per (n,c)
// ---------------------------------------------------------------------------
__global__ void stats_kernel(float* __restrict__ ws) {
    const int co  = blockIdx.x;
    const int t   = threadIdx.x;   // 64
    float s1 = ws[WS_P1 + co * 128 + t] + ws[WS_P1 + co * 128 + t + 64];
    float s2 = ws[WS_P2 + co * 128 + t] + ws[WS_P2 + co * 128 + t + 64];
#pragma unroll
    for (int m = 1; m < 64; m <<= 1) { s1 += __shfl_xor(s1, m); s2 += __shfl_xor(s2, m); }
    if (t == 0) {
        const float inv = 1.f / 65536.f;
        float mu  = s1 * inv;
        float var = s2 * inv - mu * mu;
        ws[WS_MU + co]   = mu;
        ws[WS_RSTD + co] = 1.f / sqrtf(var + 1e-5f);
    }
}

// ---------------------------------------------------------------------------
// Normalize + LeakyReLU(0.2), in place on d_out
// ---------------------------------------------------------------------------
__global__ void norm_kernel(float* __restrict__ out, const float* __restrict__ ws) {
    const int total = NB * COUT * H2 * W2 / 4;
    for (int idx = blockIdx.x * blockDim.x + threadIdx.x; idx < total;
         idx += gridDim.x * blockDim.x) {
        int co = idx >> 14;
        float mu = ws[WS_MU + co];
        float rs = ws[WS_RSTD + co];
        float4 v = ((float4*)out)[idx];
        float* p = (float*)&v;
#pragma unroll
        for (int j = 0; j < 4; ++j) {
            float t = (p[j] - mu) * rs;
            p[j] = (t >= 0.f) ? t : 0.2f * t;
        }
        ((float4*)out)[idx] = v;
    }
}

extern "C" void kernel_launch(void* const* d_in, const int* in_sizes, int n_in,
                              void* d_out, int out_size, void* d_ws, size_t ws_size,
                              hipStream_t stream) {
    const float* img = (const float*)d_in[0];
    const float* wgt = (const float*)d_in[1];
    float* out = (float*)d_out;
    float* ws  = (float*)d_ws;

    setup_w<<<32, 256, 0, stream>>>(wgt, ws);
    conv_kernel<<<NB * 128, 256, 0, stream>>>(img, out, ws);
    stats_kernel<<<256, 64, 0, stream>>>(ws);
    norm_kernel<<<2048, 256, 0, stream>>>(out, ws);
}

// Round 5
// 185.874 us; speedup vs baseline: 3.4232x; 3.4232x over previous
//
#include <hip/hip_runtime.h>

#define NB 4
#define CIN 64
#define COUT 64
#define H 128
#define W 128
#define H2 256
#define W2 256
#define HS 24             // halo LDS row stride (dwords)

// ws layout (float units)
#define WS_W    0         // bf16 weights ushort[32][64][32] = 32768 floats
#define WS_P1   32768     // per-tile partial sums  [4*64][256]
#define WS_P2   98304     // per-tile partial sumsq [4*64][256]
#define WS_MU   163840
#define WS_RSTD 164096

// ---------------------------------------------------------------------------
// Compile-time DISCO basis (replicates the numpy double-precision computation)
// ---------------------------------------------------------------------------
constexpr double csqrt(double x) {
    double g = x > 1.0 ? x : 1.0;
    for (int i = 0; i < 64; ++i) g = 0.5 * (g + x / g);
    return g;
}
constexpr double catan_pos(double x) {
    double f = 1.0;
    for (int i = 0; i < 6; ++i) { x = x / (1.0 + csqrt(1.0 + x * x)); f *= 2.0; }
    double x2 = x * x, s = 0.0, term = x;
    for (int n = 0; n < 10; ++n) { s += term / (2 * n + 1) * ((n & 1) ? -1.0 : 1.0); term *= x2; }
    return f * s;
}
constexpr double catan2c(double y, double x) {
    const double PI = 3.141592653589793;
    if (x == 0.0 && y == 0.0) return 0.0;
    double ax = x < 0 ? -x : x, ay = y < 0 ? -y : y;
    double a = (ax >= ay) ? catan_pos(ay / ax) : (PI / 2.0 - catan_pos(ax / ay));
    if (x < 0) a = PI - a;
    return (y < 0) ? -a : a;
}

struct PsiTab { double v[81][9]; };
constexpr PsiTab compute_psi() {
    PsiTab P{};
    const double hy = 1.0 / 256.0;
    const double rcut = 0.015;
    const double dr = 0.0075;
    const double PI = 3.141592653589793;
    const double TWO_PI = 6.283185307179586;
    const double dphi = PI / 2.0;
    for (int ky = 0; ky < 9; ++ky)
        for (int kx = 0; kx < 9; ++kx) {
            double dy = (double)(ky - 4) * hy;
            double dx = (double)(kx - 4) * hy;
            double r = csqrt(dy * dy + dx * dx);
            double phi = catan2c(dy, dx);
            if (phi < 0.0) phi += TWO_PI;
            for (int k = 0; k < 9; ++k) {
                int ir = (k == 0) ? 0 : ((k - 1) / 4 + 1);
                double ctr = ir * dr;
                double ad = r > ctr ? r - ctr : ctr - r;
                double rv = (ad <= dr && r <= rcut) ? 1.0 - ad / dr : 0.0;
                double val;
                if (k == 0) val = rv;
                else {
                    int ip = (k - 1) % 4;
                    double da = phi - ip * dphi; if (da < 0) da = -da;
                    double d2 = TWO_PI - da; if (d2 < da) da = d2;
                    double pv = (da <= dphi) ? 1.0 - da / dphi : 0.0;
                    val = rv * pv;
                }
                P.v[ky * 9 + kx][k] = val * (hy * hy);
            }
        }
    return P;
}

struct TapTab {
    int nt;
    int off[48];          // dy*HS + dx (dword offset from thread base)
    float val[48][9];
    bool nz[48][9];
};
constexpr TapTab make_taps() {
    TapTab T{};
    PsiTab P = compute_psi();
    for (int ky = 0; ky < 9; ++ky)
        for (int kx = 0; kx < 9; ++kx) {
            int t = ky * 9 + kx;
            bool any = false;
            for (int k = 0; k < 9; ++k) if (P.v[t][k] != 0.0) any = true;
            if (!any) continue;
            int dy = ky - 4, dx = kx - 4;    // support guarantees |dy|,|dx| <= 3
            T.off[T.nt] = dy * HS + dx;
            for (int k = 0; k < 9; ++k) {
                T.val[T.nt][k] = (float)P.v[t][k];
                T.nz[T.nt][k] = (P.v[t][k] != 0.0);
            }
            T.nt++;
        }
    return T;
}
constexpr TapTab TT = make_taps();
constexpr int NT = TT.nt;
static_assert(NT > 0 && NT <= 48, "tap table overflow");

using f32x2  = __attribute__((ext_vector_type(2))) float;
using f32x4  = __attribute__((ext_vector_type(4))) float;
using bf16x8 = __attribute__((ext_vector_type(8))) short;

__device__ __forceinline__ unsigned short f2bf_rne(float f) {
    unsigned u = __float_as_uint(f);
    unsigned r = (u + 0x7fff + ((u >> 16) & 1)) >> 16;
    return (unsigned short)r;
}
// RTZ pack of two floats to one u32 of 2 bf16 (bias cancels in InstanceNorm)
__device__ __forceinline__ unsigned pkrtz(float a, float b) {
    return (__float_as_uint(a) >> 16) | (__float_as_uint(b) & 0xffff0000u);
}

// ---------------------------------------------------------------------------
// Setup: pre-transpose weights to bf16 wsW[g][o][32]  (kk = ch*16 + k, pads 0)
// ---------------------------------------------------------------------------
__global__ void setup_w(const float* __restrict__ wgt, float* __restrict__ ws) {
    unsigned short* wsW = (unsigned short*)(ws + WS_W);
    const int g = blockIdx.x;          // channel pair 0..31
    const int t = threadIdx.x;         // 256
    const int o = t >> 2;
    const int k0 = (t & 3) * 8;
#pragma unroll
    for (int j = 0; j < 8; ++j) {
        int kk = k0 + j;
        int ch = kk >> 4, k = kk & 15;
        float v = (k < 9) ? wgt[((size_t)o * CIN + 2 * g + ch) * 9 + k] : 0.f;
        wsW[g * 2048 + o * 32 + kk] = f2bf_rne(v);
    }
}

// ---------------------------------------------------------------------------
// Fused upsample + DISCO conv. Block = 16x16 px tile (256 px), 4 waves.
// Halo staged CHANNEL-PAIRED: dword = {bf16 ch0(px), bf16 ch1(px)} so one
// ds_read_b32 feeds the tap for both channels; z accum in f32x2 (pk_fma).
// zbuf bf16 [256][40] -> MFMA 16x16x32 over K = 2ch x 16 (pads zero).
// ---------------------------------------------------------------------------
__global__ __launch_bounds__(256, 2) void conv_kernel(const float* __restrict__ img,
                                                      float* __restrict__ out,
                                                      float* __restrict__ ws) {
    __shared__ unsigned short zbuf[256][40];   // [px][kk] bf16, 80B row
    __shared__ unsigned halo[2][22 * HS];      // [buf][hy*HS+hx] ch-paired bf16x2
    __shared__ float red1[4][64], red2[4][64];

    const int tid  = threadIdx.x;
    const int bid  = blockIdx.x;
    const int n    = bid >> 8;
    const int tile = bid & 255;
    const int ty0  = (tile >> 4) << 4;
    const int tx0  = (tile & 15) << 4;

    const int r = tid >> 4, c = tid & 15;
    const int hbase = (r + 3) * HS + (c + 3);
    const int wv  = tid >> 6;
    const int l   = tid & 63;
    const int a16 = l & 15;
    const int kseg = (l >> 4) * 8;

    const unsigned short* wsW = (const unsigned short*)(ws + WS_W);

    // zero zbuf once (pads stay zero forever)
    {
        uint4* zr = (uint4*)&zbuf[0][0];
#pragma unroll
        for (int j = 0; j < 5; ++j) zr[tid + j * 256] = make_uint4(0, 0, 0, 0);
    }

    const float cs = (float)(127.0 / 255.0);

    // ---- T14 split staging: issue loads early, lerp+write after compute ----
    float Lr[2][8];
    float sFY[2], sFX[2];
    int   sIdx[2];
    bool  sZF[2];

    auto stage_issue = [&](int g) {
        const float* im0 = img + ((size_t)n * CIN + 2 * g) * (H * W);
        const float* im1 = im0 + H * W;
#pragma unroll
        for (int j = 0; j < 2; ++j) {
            int e = tid + j * 256;
            if (e < 484) {
                int hy = e / 22, hx = e - hy * 22;
                int uy = ty0 - 3 + hy, ux = tx0 - 3 + hx;
                bool zf = ((unsigned)uy >= 256u) || ((unsigned)ux >= 256u);
                float syf = (float)uy * cs;
                float sxf = (float)ux * cs;
                int y0 = (int)syf; y0 = min(max(y0, 0), 127);
                int x0 = (int)sxf; x0 = min(max(x0, 0), 127);
                int y1 = min(y0 + 1, 127), x1 = min(x0 + 1, 127);
                sFY[j] = syf - (float)y0;
                sFX[j] = sxf - (float)x0;
                sIdx[j] = hy * HS + hx;
                sZF[j] = zf;
                int b00 = y0 * W + x0, b01 = y0 * W + x1;
                int b10 = y1 * W + x0, b11 = y1 * W + x1;
                Lr[j][0] = im0[b00]; Lr[j][1] = im0[b01];
                Lr[j][2] = im0[b10]; Lr[j][3] = im0[b11];
                Lr[j][4] = im1[b00]; Lr[j][5] = im1[b01];
                Lr[j][6] = im1[b10]; Lr[j][7] = im1[b11];
            }
        }
    };
    auto stage_commit = [&](int b) {
#pragma unroll
        for (int j = 0; j < 2; ++j) {
            int e = tid + j * 256;
            if (e < 484) {
                float fy = sFY[j], fx = sFX[j];
                float t0 = Lr[j][0] + fy * (Lr[j][2] - Lr[j][0]);
                float t1 = Lr[j][1] + fy * (Lr[j][3] - Lr[j][1]);
                float v0 = t0 + fx * (t1 - t0);
                float u0 = Lr[j][4] + fy * (Lr[j][6] - Lr[j][4]);
                float u1 = Lr[j][5] + fy * (Lr[j][7] - Lr[j][5]);
                float v1 = u0 + fx * (u1 - u0);
                if (sZF[j]) { v0 = 0.f; v1 = 0.f; }
                halo[b][sIdx[j]] = (unsigned)f2bf_rne(v0) | ((unsigned)f2bf_rne(v1) << 16);
            }
        }
    };

    auto zphase = [&](int b) {
        const unsigned* hb = &halo[b][0];
        f32x2 z[9];
#pragma unroll
        for (int k = 0; k < 9; ++k) z[k] = (f32x2){0.f, 0.f};
#pragma unroll
        for (int t = 0; t < NT; ++t) {
            unsigned d = hb[hbase + TT.off[t]];
            f32x2 h = (f32x2){__uint_as_float(d << 16), __uint_as_float(d & 0xffff0000u)};
#pragma unroll
            for (int k = 0; k < 9; ++k)
                if (TT.nz[t][k]) z[k] += h * TT.val[t][k];
        }
        *(uint4*)&zbuf[tid][0] = make_uint4(pkrtz(z[0].x, z[1].x), pkrtz(z[2].x, z[3].x),
                                            pkrtz(z[4].x, z[5].x), pkrtz(z[6].x, z[7].x));
        *(unsigned*)&zbuf[tid][8] = __float_as_uint(z[8].x) >> 16;
        *(uint4*)&zbuf[tid][16] = make_uint4(pkrtz(z[0].y, z[1].y), pkrtz(z[2].y, z[3].y),
                                             pkrtz(z[4].y, z[5].y), pkrtz(z[6].y, z[7].y));
        *(unsigned*)&zbuf[tid][24] = __float_as_uint(z[8].y) >> 16;
    };

    f32x4 acc[4][4];
#pragma unroll
    for (int m = 0; m < 4; ++m)
#pragma unroll
        for (int t = 0; t < 4; ++t) acc[m][t] = (f32x4){0.f, 0.f, 0.f, 0.f};

    stage_issue(0);
    stage_commit(0);
    int cur = 0;

#pragma unroll 1
    for (int g = 0; g < 32; ++g) {
        __syncthreads();   // halo[cur] staged; prev MFMA zbuf reads done
        // A-fragments direct from global (L2-hot)
        bf16x8 af[4];
        {
            const unsigned short* wp = wsW + g * 2048 + a16 * 32 + kseg;
#pragma unroll
            for (int m = 0; m < 4; ++m)
                af[m] = *(const bf16x8*)(wp + m * 512);
        }
        if (g < 31) stage_issue(g + 1);    // global loads overlap zphase
        zphase(cur);
        if (g < 31) stage_commit(cur ^ 1);
        __syncthreads();   // zbuf + halo[nxt] ready

        bf16x8 bfr[4];
#pragma unroll
        for (int t = 0; t < 4; ++t)
            bfr[t] = *(const bf16x8*)&zbuf[wv * 64 + t * 16 + a16][kseg];
#pragma unroll
        for (int m = 0; m < 4; ++m)
#pragma unroll
            for (int t = 0; t < 4; ++t)
                acc[m][t] = __builtin_amdgcn_mfma_f32_16x16x32_bf16(af[m], bfr[t], acc[m][t], 0, 0, 0);
        cur ^= 1;
    }

    // ---- epilogue: instance-norm partials + store y ----
#pragma unroll
    for (int m = 0; m < 4; ++m) {
#pragma unroll
        for (int r4 = 0; r4 < 4; ++r4) {
            float s = 0.f, q = 0.f;
#pragma unroll
            for (int t = 0; t < 4; ++t) {
                float v = acc[m][t][r4];
                s += v; q = fmaf(v, v, q);
            }
#pragma unroll
            for (int msk = 1; msk < 16; msk <<= 1) {
                s += __shfl_xor(s, msk);
                q += __shfl_xor(q, msk);
            }
            if (a16 == 0) {
                int o = m * 16 + (l >> 4) * 4 + r4;
                red1[wv][o] = s;
                red2[wv][o] = q;
            }
        }
    }

    const size_t nbase = (size_t)n * COUT * (H2 * W2);
#pragma unroll
    for (int m = 0; m < 4; ++m)
#pragma unroll
        for (int t = 0; t < 4; ++t) {
            int Y = ty0 + wv * 4 + t;
            int X = tx0 + a16;
#pragma unroll
            for (int r4 = 0; r4 < 4; ++r4) {
                int o = m * 16 + (l >> 4) * 4 + r4;
                out[nbase + (size_t)o * (H2 * W2) + Y * W2 + X] = acc[m][t][r4];
            }
        }
    __syncthreads();
    if (tid < 64) {
        float S1 = red1[0][tid] + red1[1][tid] + red1[2][tid] + red1[3][tid];
        float S2 = red2[0][tid] + red2[1][tid] + red2[2][tid] + red2[3][tid];
        ws[WS_P1 + (n * COUT + tid) * 256 + tile] = S1;
        ws[WS_P2 + (n * COUT + tid) * 256 + tile] = S2;
    }
}

// ---------------------------------------------------------------------------
// Stats: reduce 256 tile-partials per (n,c)
// ---------------------------------------------------------------------------
__global__ void stats_kernel(float* __restrict__ ws) {
    const int co  = blockIdx.x;
    const int tid = threadIdx.x;   // 256
    float s1 = ws[WS_P1 + co * 256 + tid];
    float s2 = ws[WS_P2 + co * 256 + tid];
#pragma unroll
    for (int m = 1; m < 64; m <<= 1) { s1 += __shfl_xor(s1, m); s2 += __shfl_xor(s2, m); }
    __shared__ float r1[4], r2[4];
    if ((tid & 63) == 0) { r1[tid >> 6] = s1; r2[tid >> 6] = s2; }
    __syncthreads();
    if (tid == 0) {
        float S1 = r1[0] + r1[1] + r1[2] + r1[3];
        float S2 = r2[0] + r2[1] + r2[2] + r2[3];
        const float inv = 1.f / 65536.f;
        float mu  = S1 * inv;
        float var = S2 * inv - mu * mu;
        ws[WS_MU + co]   = mu;
        ws[WS_RSTD + co] = 1.f / sqrtf(var + 1e-5f);
    }
}

// ---------------------------------------------------------------------------
// Normalize + LeakyReLU(0.2), in place on d_out
// ---------------------------------------------------------------------------
__global__ void norm_kernel(float* __restrict__ out, const float* __restrict__ ws) {
    const int total = NB * COUT * H2 * W2 / 4;
    for (int idx = blockIdx.x * blockDim.x + threadIdx.x; idx < total;
         idx += gridDim.x * blockDim.x) {
        int co = idx >> 14;
        float mu = ws[WS_MU + co];
        float rs = ws[WS_RSTD + co];
        float4 v = ((float4*)out)[idx];
        float* p = (float*)&v;
#pragma unroll
        for (int j = 0; j < 4; ++j) {
            float t = (p[j] - mu) * rs;
            p[j] = (t >= 0.f) ? t : 0.2f * t;
        }
        ((float4*)out)[idx] = v;
    }
}

extern "C" void kernel_launch(void* const* d_in, const int* in_sizes, int n_in,
                              void* d_out, int out_size, void* d_ws, size_t ws_size,
                              hipStream_t stream) {
    const float* img = (const float*)d_in[0];
    const float* wgt = (const float*)d_in[1];
    float* out = (float*)d_out;
    float* ws  = (float*)d_ws;

    setup_w<<<32, 256, 0, stream>>>(wgt, ws);
    conv_kernel<<<NB * 256, 256, 0, stream>>>(img, out, ws);
    stats_kernel<<<256, 256, 0, stream>>>(ws);
    norm_kernel<<<2048, 256, 0, stream>>>(out, ws);
}